// Round 9
// baseline (46473.471 us; speedup 1.0000x reference)
//
#include <hip/hip_runtime.h>
#include <cmath>

// ---------------- problem constants ----------------
constexpr int S = 4, B = 8, L = 64, E = 128, H = 512, H3 = 1536, NOP = 16, SL = 256;

// ---------------- workspace layout (float slots; doubles use 2 slots) ----------------
constexpr size_t WS_H    = 0;                                  // [2 layers][2 dir][B][H] GRU carry (ZERO-INIT)
constexpr size_t WS_EMB  = WS_H + (size_t)2*2*B*H;             // [S][B][L][E]
constexpr size_t WS_XG0  = WS_EMB + (size_t)S*B*L*E;           // [2][L][B][H3]
constexpr size_t WS_XG1  = WS_XG0 + (size_t)2*L*B*H3;          // [2][L][B][H3]
constexpr size_t WS_X1   = WS_XG1 + (size_t)2*L*B*H3;          // [B][L][2H]
constexpr size_t WS_O1   = WS_X1 + (size_t)B*L*2*H;            // [B][L][2H]
constexpr size_t WS_SQ   = WS_O1 + (size_t)B*L*2*H;            // [B][SL] f32
constexpr size_t WS_DIST = WS_SQ + (size_t)B*SL;               // [B][SL][SL] f32
constexpr size_t WS_BSUM = WS_DIST + (size_t)B*SL*SL;          // [2048] f64 block sums
constexpr size_t WS_MEAND= WS_BSUM + (size_t)2*2048;           // 1 f64
constexpr size_t WS_QPW  = WS_MEAND + 2;                       // [S][B][L][H]
constexpr size_t WS_NODE = WS_QPW + (size_t)S*B*L*H;           // [S][B][L][H]
constexpr size_t WS_EN   = WS_NODE + (size_t)S*B*L*H;          // [S][B][L]
constexpr size_t WS_DEN  = WS_EN + (size_t)S*B*L;              // [S][B][L]
constexpr size_t WS_CTX  = WS_DEN + (size_t)S*B*L;             // [S][B][L][H]
constexpr size_t WS_XSP  = WS_CTX + (size_t)S*B*L*H;           // [B][S][H]
constexpr size_t WS_SC   = WS_XSP + (size_t)B*S*H;             // [B][S][S]
constexpr size_t WS_SCTX = WS_SC + (size_t)B*S*S;              // [B][S][H]

// ---------------- output layout (floats, concat in return order) ----------------
constexpr size_t O_SPAN = 0;                                   // span_output (B,S,H)
constexpr size_t O_WORD = O_SPAN + (size_t)B*S*H;              // word_out (S,B,L,H)
constexpr size_t O_WOP  = O_WORD + (size_t)S*B*L*H;            // word_operator (B,SL,NOP)
constexpr size_t O_WW   = O_WOP + (size_t)B*SL*NOP;            // word_word (B,SL,SL)
constexpr size_t O_DEP  = O_WW + (size_t)B*SL*SL;              // depend_relation (S,B,L,L)
constexpr size_t O_SH   = O_DEP + (size_t)S*B*L*L;             // span_hidden (1,B,H)

__device__ __forceinline__ float sigmoidf_(float x) { return 1.f / (1.f + expf(-x)); }

__device__ __forceinline__ float waveRedSum(float v) {
  v += __shfl_xor(v, 1);  v += __shfl_xor(v, 2);  v += __shfl_xor(v, 4);
  v += __shfl_xor(v, 8);  v += __shfl_xor(v, 16); v += __shfl_xor(v, 32);
  return v;
}
__device__ __forceinline__ double waveRedSumD(double v) {
  v += __shfl_xor(v, 1);  v += __shfl_xor(v, 2);  v += __shfl_xor(v, 4);
  v += __shfl_xor(v, 8);  v += __shfl_xor(v, 16); v += __shfl_xor(v, 32);
  return v;
}

// ---------------- embedding gather ----------------
__global__ void k_embed(const int* __restrict__ iv, const float* __restrict__ emb,
                        float* __restrict__ out) {
  int i = blockIdx.x * 256 + threadIdx.x;     // S*B*L*E = 262144
  int row = i >> 7, e = i & 127;
  out[i] = emb[(size_t)iv[row] * E + e];
}

// ---------------- word_operator ----------------
__global__ void k_wordop(const float* __restrict__ embsble, const float* __restrict__ Wk,
                         float* __restrict__ out) {
  __shared__ float wk[E * NOP];
  int tid = threadIdx.x;
  for (int r = tid; r < E * NOP; r += 256) wk[r] = Wk[r];
  __syncthreads();
  int gid = blockIdx.x * 256 + tid;           // 32768
  int row = gid >> 4, op = gid & 15;
  int s = row >> 9, b = (row >> 6) & 7, l = row & 63;
  const float* er = embsble + (size_t)row * E;
  float acc = 0.f;
  #pragma unroll 8
  for (int e = 0; e < E; ++e) acc += er[e] * wk[e * NOP + op];
  out[((size_t)b * SL + s * L + l) * NOP + op] = acc;
}

// ---------------- sq[b][n] = |row|^2 in f32, 4-accumulator order ----------------
__global__ void k_sq(const float* __restrict__ embsble, float* __restrict__ sq) {
  int gid = blockIdx.x * 256 + threadIdx.x;   // B*SL = 2048
  int b = gid >> 8, n = gid & 255;
  int sn = n >> 6, ln = n & 63;
  const float4* r4 = (const float4*)(embsble + ((size_t)(sn * 8 + b) * 64 + ln) * E);
  float a0 = 0.f, a1 = 0.f, a2 = 0.f, a3 = 0.f;
  #pragma unroll 8
  for (int e = 0; e < E / 4; ++e) {
    float4 v = r4[e];
    a0 += v.x * v.x; a1 += v.y * v.y; a2 += v.z * v.z; a3 += v.w * v.w;
  }
  sq[gid] = (a0 + a1) + (a2 + a3);
}

// ---------------- dist[b][n][m] f32 (sequential-FMA dot: order differs from k_sq
// so diagonal d2 carries an order-residual like the reference's sum-vs-einsum) +
// exact f64 per-block sum for the mean ----------------
__global__ __launch_bounds__(256) void k_dist(const float* __restrict__ embsble,
                                              const float* __restrict__ sq,
                                              float* __restrict__ dist,
                                              double* __restrict__ bsum) {
  int bi = blockIdx.x;                        // b*256 + n  (2048 blocks)
  int b = bi >> 8, n = bi & 255;
  int m = threadIdx.x;
  __shared__ float an[E];
  __shared__ double red[4];
  int sn = n >> 6, ln = n & 63;
  const float* rn = embsble + ((size_t)(sn * 8 + b) * 64 + ln) * E;
  if (m < E) an[m] = rn[m];
  __syncthreads();
  int sm = m >> 6, lm = m & 63;
  const float* rm = embsble + ((size_t)(sm * 8 + b) * 64 + lm) * E;
  float dot = 0.f;
  for (int e = 0; e < E; ++e) dot = fmaf(an[e], rm[e], dot);   // single sequential chain
  float s2 = sq[b * SL + n] + sq[b * SL + m];
  float d2 = s2 - 2.f * dot;                                   // 2*dot exact; one rounding
  float dv = sqrtf(fmaxf(d2, 0.f) + 1e-12f);
  dist[(size_t)bi * SL + m] = dv;
  double v = waveRedSumD((double)dv);
  int wid = threadIdx.x >> 6;
  if ((threadIdx.x & 63) == 0) red[wid] = v;
  __syncthreads();
  if (threadIdx.x == 0) bsum[bi] = red[0] + red[1] + red[2] + red[3];
}

// ---------------- deterministic final mean (single block, f64) ----------------
__global__ __launch_bounds__(256) void k_meansum(const double* __restrict__ bsum,
                                                 double* __restrict__ meand) {
  __shared__ double red[4];
  int tid = threadIdx.x;
  double acc = 0.0;
  for (int i = tid; i < 2048; i += 256) acc += bsum[i];
  double v = waveRedSumD(acc);
  int wid = tid >> 6;
  if ((tid & 63) == 0) red[wid] = v;
  __syncthreads();
  if (tid == 0) meand[0] = (red[0] + red[1] + red[2] + red[3]) / ((double)B * SL * SL);
}

// ---------------- word_word = where(sigmoid(-dist+mean) < 0.5, 0, .) in f32 ----------------
__global__ void k_wordword(const float* __restrict__ dist, const double* __restrict__ meand,
                           float* __restrict__ out) {
  float mean = (float)meand[0];
  int i = blockIdx.x * 256 + threadIdx.x;     // 524288
  float dis = mean - dist[i];                 // f32, mirrors ref: -dist + mean
  float sg = 1.f / (1.f + expf(-dis));
  out[i] = (sg < 0.5f) ? 0.f : sg;
}

// ---------------- depend_relation = P^T + P + I ----------------
__global__ void k_depend(const int* __restrict__ parent, float* __restrict__ out) {
  int i = blockIdx.x * 256 + threadIdx.x;     // 131072: ((sb)*64+r)*64+c
  int c = i & 63, r = (i >> 6) & 63, sb = i >> 12;
  const int* p = parent + sb * 64;
  float v = (r == c) ? 1.f : 0.f;
  if (p[r] >= 0 && p[r] == c) v += 1.f;
  if (p[c] >= 0 && p[c] == r) v += 1.f;
  out[i] = v;
}

// ---------------- xg GEMM: out[dir][t][b][g] = A[b*64+t] . W[dir*1536+g] + bias ----------------
__global__ __launch_bounds__(256) void k_gemm_xg(const float* __restrict__ A,
                                                 const float* __restrict__ W,
                                                 const float* __restrict__ bias,
                                                 float* __restrict__ out, int K) {
  __shared__ float As[32][68];
  __shared__ float Ws[32][68];
  const int tid = threadIdx.x;
  const int tx = tid & 15, ty = tid >> 4;
  const int m0 = blockIdx.x * 64;             // M = 512
  const int n0 = blockIdx.y * 64;             // N = 3072
  float acc[4][4] = {};
  for (int kc = 0; kc < K; kc += 32) {
    __syncthreads();
    #pragma unroll
    for (int r = 0; r < 8; ++r) {
      int idx = r * 256 + tid;
      int kl = idx & 31, ml = idx >> 5;
      As[kl][ml] = A[(size_t)(m0 + ml) * K + kc + kl];
      Ws[kl][ml] = W[(size_t)(n0 + ml) * K + kc + kl];
    }
    __syncthreads();
    #pragma unroll
    for (int kk = 0; kk < 32; ++kk) {
      float4 a = *(const float4*)&As[kk][ty * 4];
      float4 w = *(const float4*)&Ws[kk][tx * 4];
      float av[4] = {a.x, a.y, a.z, a.w};
      float wv[4] = {w.x, w.y, w.z, w.w};
      #pragma unroll
      for (int i = 0; i < 4; ++i)
        #pragma unroll
        for (int j = 0; j < 4; ++j) acc[i][j] += av[i] * wv[j];
    }
  }
  #pragma unroll
  for (int i = 0; i < 4; ++i) {
    int m = m0 + ty * 4 + i;
    int b = m >> 6, t = m & 63;
    #pragma unroll
    for (int j = 0; j < 4; ++j) {
      int n = n0 + tx * 4 + j;
      int dir = (n >= H3) ? 1 : 0;
      int g = n - dir * H3;
      out[((size_t)(dir * 64 + t) * B + b) * H3 + g] = acc[i][j] + bias[n];
    }
  }
}

// ---------------- GRU: one WG per (dir,b); 64 steps ----------------
__global__ __launch_bounds__(1024) void k_gru(const float* __restrict__ xg,   // [2][64][8][1536]
                                              const float* __restrict__ Whh,  // [2][1536][512]
                                              const float* __restrict__ bhh,  // [2][1536]
                                              float* __restrict__ hstate,     // [2][8][512]
                                              float* __restrict__ obuf) {     // [8][64][1024]
  const int dir = blockIdx.x & 1;
  const int b   = blockIdx.x >> 1;
  const int tid = threadIdx.x;
  const int j   = tid >> 1;
  const int half = tid & 1;
  __shared__ float hl[H];
  if (tid < H) hl[tid] = hstate[(size_t)(dir * B + b) * H + tid];
  __syncthreads();
  const float4* wr4 = (const float4*)(Whh + ((size_t)dir * H3 + j) * H + half * 256);
  const float4* wz4 = (const float4*)(Whh + ((size_t)dir * H3 + 512 + j) * H + half * 256);
  const float4* wn4 = (const float4*)(Whh + ((size_t)dir * H3 + 1024 + j) * H + half * 256);
  const float br = bhh[dir * H3 + j];
  const float bz = bhh[dir * H3 + 512 + j];
  const float bn = bhh[dir * H3 + 1024 + j];
  for (int step = 0; step < 64; ++step) {
    const int t = dir ? (63 - step) : step;
    float pr = 0.f, pz = 0.f, pn = 0.f;
    const float4* h4 = ((const float4*)hl) + half * 64;
    #pragma unroll 4
    for (int k = 0; k < 64; ++k) {
      float4 hv = h4[k];
      float4 a = wr4[k];
      pr += a.x * hv.x + a.y * hv.y + a.z * hv.z + a.w * hv.w;
      float4 c = wz4[k];
      pz += c.x * hv.x + c.y * hv.y + c.z * hv.z + c.w * hv.w;
      float4 d = wn4[k];
      pn += d.x * hv.x + d.y * hv.y + d.z * hv.z + d.w * hv.w;
    }
    pr += __shfl_xor(pr, 1);
    pz += __shfl_xor(pz, 1);
    pn += __shfl_xor(pn, 1);
    const float* xr = xg + ((size_t)(dir * 64 + t) * B + b) * H3;
    float r = sigmoidf_(xr[j] + pr + br);
    float z = sigmoidf_(xr[512 + j] + pz + bz);
    float hold = hl[j];
    float n = tanhf(xr[1024 + j] + r * (pn + bn));
    float hnew = (1.f - z) * n + z * hold;
    __syncthreads();
    if (half == 0) {
      hl[j] = hnew;
      obuf[((size_t)b * 64 + t) * (2 * H) + dir * H + j] = hnew;
    }
    __syncthreads();
  }
  if (tid < H) hstate[(size_t)(dir * B + b) * H + tid] = hl[tid];
}

// ---------------- word_out[s] = o1f + o1b ----------------
__global__ void k_addwo(const float* __restrict__ o1, float* __restrict__ wout_s) {
  int i = blockIdx.x * 256 + threadIdx.x;     // 262144: (b*64+t)*512+j
  int j = i & 511; int bt = i >> 9;
  wout_s[i] = o1[(size_t)bt * (2 * H) + j] + o1[(size_t)bt * (2 * H) + H + j];
}

// ---------------- qpw gather + node_vec init ----------------
__global__ void k_qpwnode(const float* __restrict__ wout, const int* __restrict__ parent,
                          float* __restrict__ qpw, float* __restrict__ node) {
  int i = blockIdx.x * 256 + threadIdx.x;     // 1048576
  int j = i & 511; int c = (i >> 9) & 63; int sb = i >> 15;
  int p = parent[sb * 64 + c]; if (p < 0) p = 0;
  qpw[i] = wout[((size_t)sb * 64 + p) * H + j];
  node[i] = wout[i];
}

// ---------------- tree energy: rows with depth==d ----------------
__global__ __launch_bounds__(512) void k_energy(const int* __restrict__ depth,
                                                const float* __restrict__ qpw,
                                                const float* __restrict__ node,
                                                const float* __restrict__ Wa,
                                                const float* __restrict__ va,
                                                float* __restrict__ energy, int d) {
  int sb = blockIdx.x;                        // 32
  int tid = threadIdx.x;                      // 512
  __shared__ float cat[8][1024];
  __shared__ float red[64];
  __shared__ int clist[64];
  __shared__ int ccount;
  if (tid == 0) {
    int cnt = 0;
    for (int c = 0; c < 64; ++c) if (depth[sb * 64 + c] == d) clist[cnt++] = c;
    ccount = cnt;
  }
  __syncthreads();
  int cnt = ccount;
  for (int c0 = 0; c0 < cnt; c0 += 8) {
    int nc = min(8, cnt - c0);
    __syncthreads();
    for (int r = 0; r < 16; ++r) {
      int idx = r * 512 + tid;
      int cc = idx >> 10, i = idx & 1023;
      if (cc < nc) {
        int c = clist[c0 + cc];
        size_t base = ((size_t)sb * 64 + c) * H;
        cat[cc][i] = (i < H) ? qpw[base + i] : node[base + i - H];
      }
    }
    __syncthreads();
    float acc[8] = {0, 0, 0, 0, 0, 0, 0, 0};
    for (int i = 0; i < 1024; ++i) {
      float w = Wa[(size_t)i * H + tid];
      #pragma unroll
      for (int cc = 0; cc < 8; ++cc) acc[cc] += cat[cc][i] * w;
    }
    float vj = va[tid];
    int lane = tid & 63, wid = tid >> 6;
    for (int cc = 0; cc < nc; ++cc) {
      float v = waveRedSum(vj * tanhf(acc[cc]));
      if (lane == 0) red[cc * 8 + wid] = v;
    }
    __syncthreads();
    if (tid < nc) {
      float e = 0.f;
      for (int w = 0; w < 8; ++w) e += red[tid * 8 + w];
      energy[sb * 64 + clist[c0 + tid]] = e;
    }
  }
}

// ---------------- masked max, exp, scatter-to-parent ----------------
__global__ __launch_bounds__(512) void k_scatter(const int* __restrict__ depth,
                                                 const int* __restrict__ parent,
                                                 const float* __restrict__ energy,
                                                 const float* __restrict__ node,
                                                 float* __restrict__ denom,
                                                 float* __restrict__ ctx, int d) {
  int sb = blockIdx.x, tid = threadIdx.x;
  size_t cbase = (size_t)sb * 64 * H;
  for (int idx = tid; idx < 64 * H; idx += 512) ctx[cbase + idx] = 0.f;
  if (tid < 64) denom[sb * 64 + tid] = 0.f;
  __shared__ float mred;
  if (tid < 64) {
    float en = -INFINITY;
    if (depth[sb * 64 + tid] == d) en = energy[sb * 64 + tid];
    en = fmaxf(en, __shfl_xor(en, 1));  en = fmaxf(en, __shfl_xor(en, 2));
    en = fmaxf(en, __shfl_xor(en, 4));  en = fmaxf(en, __shfl_xor(en, 8));
    en = fmaxf(en, __shfl_xor(en, 16)); en = fmaxf(en, __shfl_xor(en, 32));
    if (tid == 0) mred = en;
  }
  __syncthreads();
  float m = mred;
  if (m == -INFINITY) return;
  for (int c = 0; c < 64; ++c) {
    if (depth[sb * 64 + c] != d) continue;
    float e = expf(energy[sb * 64 + c] - m);
    int p = parent[sb * 64 + c];
    ctx[cbase + (size_t)p * H + tid] += e * node[cbase + (size_t)c * H + tid];
    if (tid == 0) denom[sb * 64 + p] += e;
  }
}

// ---------------- parent update ----------------
__global__ __launch_bounds__(512) void k_update(const float* __restrict__ denom,
                                                const float* __restrict__ ctx,
                                                const float* __restrict__ wout,
                                                const float* __restrict__ Wc,
                                                float* __restrict__ node) {
  int sb = blockIdx.x, tid = threadIdx.x;
  __shared__ float cat[8][1024];
  __shared__ int plist[64];
  __shared__ int pcount;
  if (tid == 0) {
    int cnt = 0;
    for (int p = 0; p < 64; ++p) if (denom[sb * 64 + p] > 0.f) plist[cnt++] = p;
    pcount = cnt;
  }
  __syncthreads();
  int cnt = pcount;
  for (int p0 = 0; p0 < cnt; p0 += 8) {
    int nc = min(8, cnt - p0);
    __syncthreads();
    for (int r = 0; r < 16; ++r) {
      int idx = r * 512 + tid;
      int cc = idx >> 10, i = idx & 1023;
      if (cc < nc) {
        int p = plist[p0 + cc];
        size_t base = ((size_t)sb * 64 + p) * H;
        cat[cc][i] = (i < H) ? (ctx[base + i] / denom[sb * 64 + p]) : wout[base + i - H];
      }
    }
    __syncthreads();
    float acc[8] = {0, 0, 0, 0, 0, 0, 0, 0};
    for (int i = 0; i < 1024; ++i) {
      float w = Wc[(size_t)i * H + tid];
      #pragma unroll
      for (int cc = 0; cc < 8; ++cc) acc[cc] += cat[cc][i] * w;
    }
    for (int cc = 0; cc < nc; ++cc) {
      int p = plist[p0 + cc];
      node[((size_t)sb * 64 + p) * H + tid] = tanhf(acc[cc]);
    }
  }
}

// ---------------- span input ----------------
__global__ void k_xsp(const float* __restrict__ node, const float* __restrict__ pe,
                      float* __restrict__ xsp) {
  int i = blockIdx.x * 256 + threadIdx.x;     // 16384: (b*4+s)*512+j
  int j = i & 511, s = (i >> 9) & 3, b = i >> 11;
  xsp[i] = node[((size_t)(s * B + b) * 64 + 0) * H + j] + pe[s * H + j];
}

// ---------------- span attention scores ----------------
__global__ __launch_bounds__(512) void k_scspan(const float* __restrict__ xsp,
                                                const float* __restrict__ Wa,
                                                const float* __restrict__ va,
                                                const int* __restrict__ slen,
                                                float* __restrict__ sc) {
  int bi = blockIdx.x;                        // b*16 + q*4 + k (128 blocks)
  int b = bi >> 4, q = (bi >> 2) & 3, k = bi & 3;
  int tid = threadIdx.x;
  __shared__ float cat[1024];
  __shared__ float red[8];
  cat[tid] = xsp[(size_t)(b * S + q) * H + tid];
  cat[H + tid] = xsp[(size_t)(b * S + k) * H + tid];
  __syncthreads();
  float acc = 0.f;
  for (int i = 0; i < 1024; ++i) acc += cat[i] * Wa[(size_t)i * H + tid];
  float v = waveRedSum(va[tid] * tanhf(acc));
  int lane = tid & 63, wid = tid >> 6;
  if (lane == 0) red[wid] = v;
  __syncthreads();
  if (tid == 0) {
    float t = 0.f;
    for (int w = 0; w < 8; ++w) t += red[w];
    if (k >= slen[b]) t = -1e9f;
    sc[bi] = t;
  }
}

// ---------------- softmax over k + ctx ----------------
__global__ __launch_bounds__(512) void k_softctx(const float* __restrict__ sc,
                                                 const float* __restrict__ xsp,
                                                 float* __restrict__ sctx) {
  int bi = blockIdx.x;                        // b*4+q (32 blocks)
  int b = bi >> 2;
  int tid = threadIdx.x;
  float s0 = sc[bi * 4 + 0], s1 = sc[bi * 4 + 1], s2 = sc[bi * 4 + 2], s3 = sc[bi * 4 + 3];
  float m = fmaxf(fmaxf(s0, s1), fmaxf(s2, s3));
  float e0 = expf(s0 - m), e1 = expf(s1 - m), e2 = expf(s2 - m), e3 = expf(s3 - m);
  float inv = 1.f / (e0 + e1 + e2 + e3);
  float v = (e0 * xsp[(size_t)(b * S + 0) * H + tid] + e1 * xsp[(size_t)(b * S + 1) * H + tid] +
             e2 * xsp[(size_t)(b * S + 2) * H + tid] + e3 * xsp[(size_t)(b * S + 3) * H + tid]) * inv;
  sctx[(size_t)bi * H + tid] = v;
}

// ---------------- span output ----------------
__global__ __launch_bounds__(512) void k_spanout(const float* __restrict__ sctx,
                                                 const float* __restrict__ xsp,
                                                 const float* __restrict__ Wc,
                                                 const int* __restrict__ slen,
                                                 float* __restrict__ out) {
  int bi = blockIdx.x;                        // b*4+q (32 blocks)
  int b = bi >> 2, q = bi & 3;
  int tid = threadIdx.x;
  __shared__ float cat[1024];
  cat[tid] = sctx[(size_t)bi * H + tid];
  cat[H + tid] = xsp[(size_t)bi * H + tid];
  __syncthreads();
  float acc = 0.f;
  for (int i = 0; i < 1024; ++i) acc += cat[i] * Wc[(size_t)i * H + tid];
  float v = tanhf(acc);
  if (q >= slen[b]) v = 0.f;
  out[(size_t)bi * H + tid] = v;
}

// ---------------- span hidden ----------------
__global__ void k_spanhid(const float* __restrict__ spanout, const int* __restrict__ slen,
                          float* __restrict__ sh) {
  int i = blockIdx.x * 256 + threadIdx.x;     // 4096: b*512+j
  int b = i >> 9, j = i & 511;
  int q = slen[b] - 1;
  sh[i] = spanout[(size_t)(b * S + q) * H + j];
}

extern "C" void kernel_launch(void* const* d_in, const int* in_sizes, int n_in,
                              void* d_out, int out_size, void* d_ws, size_t ws_size,
                              hipStream_t stream) {
  (void)in_sizes; (void)n_in; (void)out_size; (void)ws_size;
  const int*   iv     = (const int*)d_in[0];
  const int*   slen   = (const int*)d_in[2];
  const int*   parent = (const int*)d_in[3];
  const int*   depth  = (const int*)d_in[4];
  const float* emb    = (const float*)d_in[5];
  const float* wih0   = (const float*)d_in[6];
  const float* whh0   = (const float*)d_in[7];
  const float* bih0   = (const float*)d_in[8];
  const float* bhh0   = (const float*)d_in[9];
  const float* wih1   = (const float*)d_in[10];
  const float* whh1   = (const float*)d_in[11];
  const float* bih1   = (const float*)d_in[12];
  const float* bhh1   = (const float*)d_in[13];
  const float* pe     = (const float*)d_in[14];
  const float* Wk     = (const float*)d_in[15];
  const float* Wa_s   = (const float*)d_in[16];
  const float* va_s   = (const float*)d_in[17];
  const float* Wc_s   = (const float*)d_in[18];
  const float* Wa_p   = (const float*)d_in[19];
  const float* va_p   = (const float*)d_in[20];
  const float* Wc_p   = (const float*)d_in[21];
  float* ws  = (float*)d_ws;
  float* out = (float*)d_out;

  // zero GRU hidden carry
  hipMemsetAsync(ws, 0, (2 * 2 * B * H) * sizeof(float), stream);

  k_embed<<<1024, 256, 0, stream>>>(iv, emb, ws + WS_EMB);
  k_wordop<<<128, 256, 0, stream>>>(ws + WS_EMB, Wk, out + O_WOP);
  k_sq<<<8, 256, 0, stream>>>(ws + WS_EMB, ws + WS_SQ);
  k_dist<<<2048, 256, 0, stream>>>(ws + WS_EMB, ws + WS_SQ,
                                   ws + WS_DIST, (double*)(ws + WS_BSUM));
  k_meansum<<<1, 256, 0, stream>>>((const double*)(ws + WS_BSUM), (double*)(ws + WS_MEAND));
  k_wordword<<<2048, 256, 0, stream>>>(ws + WS_DIST, (const double*)(ws + WS_MEAND),
                                       out + O_WW);
  k_depend<<<512, 256, 0, stream>>>(parent, out + O_DEP);

  for (int s = 0; s < S; ++s) {
    k_gemm_xg<<<dim3(8, 48), 256, 0, stream>>>(ws + WS_EMB + (size_t)s * B * L * E, wih0, bih0,
                                               ws + WS_XG0, E);
    k_gru<<<16, 1024, 0, stream>>>(ws + WS_XG0, whh0, bhh0, ws + WS_H, ws + WS_X1);
    k_gemm_xg<<<dim3(8, 48), 256, 0, stream>>>(ws + WS_X1, wih1, bih1, ws + WS_XG1, 2 * H);
    k_gru<<<16, 1024, 0, stream>>>(ws + WS_XG1, whh1, bhh1, ws + WS_H + 2 * B * H, ws + WS_O1);
    k_addwo<<<1024, 256, 0, stream>>>(ws + WS_O1, out + O_WORD + (size_t)s * B * L * H);
  }

  k_qpwnode<<<4096, 256, 0, stream>>>(out + O_WORD, parent, ws + WS_QPW, ws + WS_NODE);
  for (int d = 10; d >= 1; --d) {
    k_energy<<<32, 512, 0, stream>>>(depth, ws + WS_QPW, ws + WS_NODE, Wa_p, va_p, ws + WS_EN, d);
    k_scatter<<<32, 512, 0, stream>>>(depth, parent, ws + WS_EN, ws + WS_NODE,
                                      ws + WS_DEN, ws + WS_CTX, d);
    k_update<<<32, 512, 0, stream>>>(ws + WS_DEN, ws + WS_CTX, out + O_WORD, Wc_p, ws + WS_NODE);
  }

  k_xsp<<<64, 256, 0, stream>>>(ws + WS_NODE, pe, ws + WS_XSP);
  k_scspan<<<128, 512, 0, stream>>>(ws + WS_XSP, Wa_s, va_s, slen, ws + WS_SC);
  k_softctx<<<32, 512, 0, stream>>>(ws + WS_SC, ws + WS_XSP, ws + WS_SCTX);
  k_spanout<<<32, 512, 0, stream>>>(ws + WS_SCTX, ws + WS_XSP, Wc_s, slen, out + O_SPAN);
  k_spanhid<<<16, 256, 0, stream>>>(out + O_SPAN, slen, out + O_SH);
}

// Round 13
// 8863.490 us; speedup vs baseline: 5.2432x; 5.2432x over previous
//
#include <hip/hip_runtime.h>
#include <cmath>

typedef unsigned short ushort_t;
typedef unsigned int uint_t;

// ---------------- problem constants ----------------
constexpr int S = 4, B = 8, L = 64, E = 128, H = 512, H3 = 1536, NOP = 16, SL = 256;

// ---------------- workspace layout (float slots; doubles use 2 slots) ----------------
constexpr size_t WS_H    = 0;                                  // [2 layers][2 dir][B][H] GRU carry (ZERO-INIT)
constexpr size_t WS_EMB  = WS_H + (size_t)2*2*B*H;             // [S][B][L][E]
constexpr size_t WS_XG0  = WS_EMB + (size_t)S*B*L*E;           // [2][L][B][H3]
constexpr size_t WS_XG1  = WS_XG0 + (size_t)2*L*B*H3;          // [2][L][B][H3]
constexpr size_t WS_X1   = WS_XG1 + (size_t)2*L*B*H3;          // [B][L][2H]
constexpr size_t WS_O1   = WS_X1 + (size_t)B*L*2*H;            // [B][L][2H]
constexpr size_t WS_SQ   = WS_O1 + (size_t)B*L*2*H;            // [B][SL] f32
constexpr size_t WS_DIST = WS_SQ + (size_t)B*SL;               // [B][SL][SL] f32
constexpr size_t WS_BSUM = WS_DIST + (size_t)B*SL*SL;          // [2048] f64 block sums
constexpr size_t WS_MEAND= WS_BSUM + (size_t)2*2048;           // 1 f64 (pad to 4 slots for alignment)
constexpr size_t WS_QPW  = WS_MEAND + 4;                       // [S][B][L][H]
constexpr size_t WS_NODE = WS_QPW + (size_t)S*B*L*H;           // [S][B][L][H]
constexpr size_t WS_EN   = WS_NODE + (size_t)S*B*L*H;          // [S][B][L]
constexpr size_t WS_DEN  = WS_EN + (size_t)S*B*L;              // [S][B][L]
constexpr size_t WS_CTX  = WS_DEN + (size_t)S*B*L;             // [S][B][L][H]
constexpr size_t WS_XSP  = WS_CTX + (size_t)S*B*L*H;           // [B][S][H]
constexpr size_t WS_SC   = WS_XSP + (size_t)B*S*H;             // [B][S][S]
constexpr size_t WS_SCTX = WS_SC + (size_t)B*S*S;              // [B][S][H]
constexpr size_t WS_WB0  = WS_SCTX + (size_t)B*S*H;            // [2][1536][512] bf16 whh0 (786432 float slots)
constexpr size_t WS_WB1  = WS_WB0 + (size_t)2*H3*H/2;          // [2][1536][512] bf16 whh1

// ---------------- output layout (floats, concat in return order) ----------------
constexpr size_t O_SPAN = 0;                                   // span_output (B,S,H)
constexpr size_t O_WORD = O_SPAN + (size_t)B*S*H;              // word_out (S,B,L,H)
constexpr size_t O_WOP  = O_WORD + (size_t)S*B*L*H;            // word_operator (B,SL,NOP)
constexpr size_t O_WW   = O_WOP + (size_t)B*SL*NOP;            // word_word (B,SL,SL)
constexpr size_t O_DEP  = O_WW + (size_t)B*SL*SL;              // depend_relation (S,B,L,L)
constexpr size_t O_SH   = O_DEP + (size_t)S*B*L*L;             // span_hidden (1,B,H)

__device__ __forceinline__ float sigmoidf_(float x) { return 1.f / (1.f + expf(-x)); }

__device__ __forceinline__ float waveRedSum(float v) {
  v += __shfl_xor(v, 1);  v += __shfl_xor(v, 2);  v += __shfl_xor(v, 4);
  v += __shfl_xor(v, 8);  v += __shfl_xor(v, 16); v += __shfl_xor(v, 32);
  return v;
}
__device__ __forceinline__ double waveRedSumD(double v) {
  v += __shfl_xor(v, 1);  v += __shfl_xor(v, 2);  v += __shfl_xor(v, 4);
  v += __shfl_xor(v, 8);  v += __shfl_xor(v, 16); v += __shfl_xor(v, 32);
  return v;
}

// ---------------- embedding gather ----------------
__global__ void k_embed(const int* __restrict__ iv, const float* __restrict__ emb,
                        float* __restrict__ out) {
  int i = blockIdx.x * 256 + threadIdx.x;     // S*B*L*E = 262144
  int row = i >> 7, e = i & 127;
  out[i] = emb[(size_t)iv[row] * E + e];
}

// ---------------- word_operator ----------------
__global__ void k_wordop(const float* __restrict__ embsble, const float* __restrict__ Wk,
                         float* __restrict__ out) {
  __shared__ float wk[E * NOP];
  int tid = threadIdx.x;
  for (int r = tid; r < E * NOP; r += 256) wk[r] = Wk[r];
  __syncthreads();
  int gid = blockIdx.x * 256 + tid;           // 32768
  int row = gid >> 4, op = gid & 15;
  int s = row >> 9, b = (row >> 6) & 7, l = row & 63;
  const float* er = embsble + (size_t)row * E;
  float acc = 0.f;
  #pragma unroll 8
  for (int e = 0; e < E; ++e) acc += er[e] * wk[e * NOP + op];
  out[((size_t)b * SL + s * L + l) * NOP + op] = acc;
}

// ---------------- sq[b][n] = |row|^2 in f32, 4-accumulator order ----------------
__global__ void k_sq(const float* __restrict__ embsble, float* __restrict__ sq) {
  int gid = blockIdx.x * 256 + threadIdx.x;   // B*SL = 2048
  int b = gid >> 8, n = gid & 255;
  int sn = n >> 6, ln = n & 63;
  const float4* r4 = (const float4*)(embsble + ((size_t)(sn * 8 + b) * 64 + ln) * E);
  float a0 = 0.f, a1 = 0.f, a2 = 0.f, a3 = 0.f;
  #pragma unroll 8
  for (int e = 0; e < E / 4; ++e) {
    float4 v = r4[e];
    a0 += v.x * v.x; a1 += v.y * v.y; a2 += v.z * v.z; a3 += v.w * v.w;
  }
  sq[gid] = (a0 + a1) + (a2 + a3);
}

// ---------------- dist[b][n][m] f32 (sequential-FMA dot; order differs from k_sq) ----------------
__global__ __launch_bounds__(256) void k_dist(const float* __restrict__ embsble,
                                              const float* __restrict__ sq,
                                              float* __restrict__ dist,
                                              double* __restrict__ bsum) {
  int bi = blockIdx.x;                        // b*256 + n  (2048 blocks)
  int b = bi >> 8, n = bi & 255;
  int m = threadIdx.x;
  __shared__ float an[E];
  __shared__ double red[4];
  int sn = n >> 6, ln = n & 63;
  const float* rn = embsble + ((size_t)(sn * 8 + b) * 64 + ln) * E;
  if (m < E) an[m] = rn[m];
  __syncthreads();
  int sm = m >> 6, lm = m & 63;
  const float* rm = embsble + ((size_t)(sm * 8 + b) * 64 + lm) * E;
  float dot = 0.f;
  for (int e = 0; e < E; ++e) dot = fmaf(an[e], rm[e], dot);   // single sequential chain
  float s2 = sq[b * SL + n] + sq[b * SL + m];
  float d2 = s2 - 2.f * dot;
  float dv = sqrtf(fmaxf(d2, 0.f) + 1e-12f);
  dist[(size_t)bi * SL + m] = dv;
  double v = waveRedSumD((double)dv);
  int wid = threadIdx.x >> 6;
  if ((threadIdx.x & 63) == 0) red[wid] = v;
  __syncthreads();
  if (threadIdx.x == 0) bsum[bi] = red[0] + red[1] + red[2] + red[3];
}

// ---------------- deterministic final mean (single block, f64) ----------------
__global__ __launch_bounds__(256) void k_meansum(const double* __restrict__ bsum,
                                                 double* __restrict__ meand) {
  __shared__ double red[4];
  int tid = threadIdx.x;
  double acc = 0.0;
  for (int i = tid; i < 2048; i += 256) acc += bsum[i];
  double v = waveRedSumD(acc);
  int wid = tid >> 6;
  if ((tid & 63) == 0) red[wid] = v;
  __syncthreads();
  if (tid == 0) meand[0] = (red[0] + red[1] + red[2] + red[3]) / ((double)B * SL * SL);
}

// ---------------- word_word = where(sigmoid(-dist+mean) < 0.5, 0, .) in f32 ----------------
__global__ void k_wordword(const float* __restrict__ dist, const double* __restrict__ meand,
                           float* __restrict__ out) {
  float mean = (float)meand[0];
  int i = blockIdx.x * 256 + threadIdx.x;     // 524288
  float dis = mean - dist[i];
  float sg = 1.f / (1.f + expf(-dis));
  out[i] = (sg < 0.5f) ? 0.f : sg;
}

// ---------------- depend_relation = P^T + P + I ----------------
__global__ void k_depend(const int* __restrict__ parent, float* __restrict__ out) {
  int i = blockIdx.x * 256 + threadIdx.x;     // 131072
  int c = i & 63, r = (i >> 6) & 63, sb = i >> 12;
  const int* p = parent + sb * 64;
  float v = (r == c) ? 1.f : 0.f;
  if (p[r] >= 0 && p[r] == c) v += 1.f;
  if (p[c] >= 0 && p[c] == r) v += 1.f;
  out[i] = v;
}

// ---------------- pack f32 -> bf16 (RNE), n = 2*1536*512 exact ----------------
__global__ void k_pack(const float* __restrict__ in, ushort_t* __restrict__ out) {
  int i = blockIdx.x * 256 + threadIdx.x;
  uint_t x = __float_as_uint(in[i]);
  uint_t r = (x + 0x7fffu + ((x >> 16) & 1u)) >> 16;
  out[i] = (ushort_t)r;
}

// ---------------- xg GEMM: out[dir][t][b][g] = A[b*64+t] . W[dir*1536+g] + bias ----------------
__global__ __launch_bounds__(256) void k_gemm_xg(const float* __restrict__ A,
                                                 const float* __restrict__ W,
                                                 const float* __restrict__ bias,
                                                 float* __restrict__ out, int K) {
  __shared__ float As[32][68];
  __shared__ float Ws[32][68];
  const int tid = threadIdx.x;
  const int tx = tid & 15, ty = tid >> 4;
  const int m0 = blockIdx.x * 64;             // M = 512
  const int n0 = blockIdx.y * 64;             // N = 3072
  float acc[4][4] = {};
  for (int kc = 0; kc < K; kc += 32) {
    __syncthreads();
    #pragma unroll
    for (int r = 0; r < 8; ++r) {
      int idx = r * 256 + tid;
      int kl = idx & 31, ml = idx >> 5;
      As[kl][ml] = A[(size_t)(m0 + ml) * K + kc + kl];
      Ws[kl][ml] = W[(size_t)(n0 + ml) * K + kc + kl];
    }
    __syncthreads();
    #pragma unroll
    for (int kk = 0; kk < 32; ++kk) {
      float4 a = *(const float4*)&As[kk][ty * 4];
      float4 w = *(const float4*)&Ws[kk][tx * 4];
      float av[4] = {a.x, a.y, a.z, a.w};
      float wv[4] = {w.x, w.y, w.z, w.w};
      #pragma unroll
      for (int i = 0; i < 4; ++i)
        #pragma unroll
        for (int j = 0; j < 4; ++j) acc[i][j] += av[i] * wv[j];
    }
  }
  #pragma unroll
  for (int i = 0; i < 4; ++i) {
    int m = m0 + ty * 4 + i;
    int b = m >> 6, t = m & 63;
    #pragma unroll
    for (int j = 0; j < 4; ++j) {
      int n = n0 + tx * 4 + j;
      int dir = (n >= H3) ? 1 : 0;
      int g = n - dir * H3;
      out[((size_t)(dir * 64 + t) * B + b) * H3 + g] = acc[i][j] + bias[n];
    }
  }
}

// ---------------- GRU: one WG per (dir,b); coalesced bf16 Whh streaming ----------------
// Per step: 16 waves × 24 passes × 4 rows; 16 lanes/row read 16 consecutive uint4
// (256B contiguous => full 64B lines); h cached in 32 VGPRs/lane; 4-level shfl
// reduce -> dot[1536] in LDS; then elementwise gate phase (tid<512).
__global__ __launch_bounds__(1024) void k_gru(const float* __restrict__ xg,      // [2][64][8][1536]
                                              const ushort_t* __restrict__ whhb, // [2][1536][512] bf16
                                              const float* __restrict__ bhh,     // [2][1536]
                                              float* __restrict__ hstate,        // [2][8][512]
                                              float* __restrict__ obuf) {        // [8][64][1024]
  const int dir = blockIdx.x & 1;
  const int b   = blockIdx.x >> 1;
  const int tid = threadIdx.x;
  const int w   = tid >> 6;                   // wave 0..15
  const int l   = tid & 63;
  const int rsub = l >> 4;                    // row-in-quad 0..3
  const int q   = l & 15;                     // col-group 0..15
  __shared__ float hl[H];
  __shared__ float dotl[H3];
  __shared__ float bsh[H3];
  for (int i = tid; i < H3; i += 1024) bsh[i] = bhh[dir * H3 + i];
  if (tid < H) hl[tid] = hstate[(size_t)(dir * B + b) * H + tid];
  __syncthreads();
  const uint4* wq = (const uint4*)whhb + (size_t)dir * H3 * 64;  // 64 uint4 per row
  for (int step = 0; step < 64; ++step) {
    const int t = dir ? (63 - step) : step;
    // cache h for this lane's col-slice: cols 8q+128tt+0..7, tt=0..3
    float4 hA[4], hB[4];
    const float4* h4 = (const float4*)hl;
    #pragma unroll
    for (int tt = 0; tt < 4; ++tt) {
      hA[tt] = h4[2 * q + 32 * tt];
      hB[tt] = h4[2 * q + 32 * tt + 1];
    }
    #pragma unroll 4
    for (int p = 0; p < 24; ++p) {
      int row = w * 96 + p * 4 + rsub;
      const uint4* wr = wq + (size_t)row * 64;
      float acc = 0.f;
      #pragma unroll
      for (int tt = 0; tt < 4; ++tt) {
        uint4 W = wr[q + 16 * tt];
        float4 ha = hA[tt], hb = hB[tt];
        acc = fmaf(__uint_as_float(W.x << 16),          ha.x, acc);
        acc = fmaf(__uint_as_float(W.x & 0xffff0000u),  ha.y, acc);
        acc = fmaf(__uint_as_float(W.y << 16),          ha.z, acc);
        acc = fmaf(__uint_as_float(W.y & 0xffff0000u),  ha.w, acc);
        acc = fmaf(__uint_as_float(W.z << 16),          hb.x, acc);
        acc = fmaf(__uint_as_float(W.z & 0xffff0000u),  hb.y, acc);
        acc = fmaf(__uint_as_float(W.w << 16),          hb.z, acc);
        acc = fmaf(__uint_as_float(W.w & 0xffff0000u),  hb.w, acc);
      }
      acc += __shfl_xor(acc, 1); acc += __shfl_xor(acc, 2);
      acc += __shfl_xor(acc, 4); acc += __shfl_xor(acc, 8);
      if (q == 0) dotl[row] = acc;
    }
    __syncthreads();
    if (tid < H) {
      int j = tid;
      const float* xr = xg + ((size_t)(dir * 64 + t) * B + b) * H3;
      float r = sigmoidf_(xr[j] + dotl[j] + bsh[j]);
      float z = sigmoidf_(xr[512 + j] + dotl[512 + j] + bsh[512 + j]);
      float n = tanhf(xr[1024 + j] + r * (dotl[1024 + j] + bsh[1024 + j]));
      float hnew = (1.f - z) * n + z * hl[j];
      hl[j] = hnew;
      obuf[((size_t)b * 64 + t) * (2 * H) + dir * H + j] = hnew;
    }
    __syncthreads();
  }
  if (tid < H) hstate[(size_t)(dir * B + b) * H + tid] = hl[tid];
}

// ---------------- word_out[s] = o1f + o1b ----------------
__global__ void k_addwo(const float* __restrict__ o1, float* __restrict__ wout_s) {
  int i = blockIdx.x * 256 + threadIdx.x;     // 262144
  int j = i & 511; int bt = i >> 9;
  wout_s[i] = o1[(size_t)bt * (2 * H) + j] + o1[(size_t)bt * (2 * H) + H + j];
}

// ---------------- qpw gather + node_vec init ----------------
__global__ void k_qpwnode(const float* __restrict__ wout, const int* __restrict__ parent,
                          float* __restrict__ qpw, float* __restrict__ node) {
  int i = blockIdx.x * 256 + threadIdx.x;     // 1048576
  int j = i & 511; int c = (i >> 9) & 63; int sb = i >> 15;
  int p = parent[sb * 64 + c]; if (p < 0) p = 0;
  qpw[i] = wout[((size_t)sb * 64 + p) * H + j];
  node[i] = wout[i];
}

// ---------------- tree energy: rows with depth==d ----------------
__global__ __launch_bounds__(512) void k_energy(const int* __restrict__ depth,
                                                const float* __restrict__ qpw,
                                                const float* __restrict__ node,
                                                const float* __restrict__ Wa,
                                                const float* __restrict__ va,
                                                float* __restrict__ energy, int d) {
  int sb = blockIdx.x;                        // 32
  int tid = threadIdx.x;                      // 512
  __shared__ float cat[8][1024];
  __shared__ float red[64];
  __shared__ int clist[64];
  __shared__ int ccount;
  if (tid == 0) {
    int cnt = 0;
    for (int c = 0; c < 64; ++c) if (depth[sb * 64 + c] == d) clist[cnt++] = c;
    ccount = cnt;
  }
  __syncthreads();
  int cnt = ccount;
  for (int c0 = 0; c0 < cnt; c0 += 8) {
    int nc = min(8, cnt - c0);
    __syncthreads();
    for (int r = 0; r < 16; ++r) {
      int idx = r * 512 + tid;
      int cc = idx >> 10, i = idx & 1023;
      if (cc < nc) {
        int c = clist[c0 + cc];
        size_t base = ((size_t)sb * 64 + c) * H;
        cat[cc][i] = (i < H) ? qpw[base + i] : node[base + i - H];
      }
    }
    __syncthreads();
    float acc[8] = {0, 0, 0, 0, 0, 0, 0, 0};
    for (int i = 0; i < 1024; ++i) {
      float w = Wa[(size_t)i * H + tid];
      #pragma unroll
      for (int cc = 0; cc < 8; ++cc) acc[cc] += cat[cc][i] * w;
    }
    float vj = va[tid];
    int lane = tid & 63, wid = tid >> 6;
    for (int cc = 0; cc < nc; ++cc) {
      float v = waveRedSum(vj * tanhf(acc[cc]));
      if (lane == 0) red[cc * 8 + wid] = v;
    }
    __syncthreads();
    if (tid < nc) {
      float e = 0.f;
      for (int w = 0; w < 8; ++w) e += red[tid * 8 + w];
      energy[sb * 64 + clist[c0 + tid]] = e;
    }
  }
}

// ---------------- masked max, exp, scatter-to-parent ----------------
__global__ __launch_bounds__(512) void k_scatter(const int* __restrict__ depth,
                                                 const int* __restrict__ parent,
                                                 const float* __restrict__ energy,
                                                 const float* __restrict__ node,
                                                 float* __restrict__ denom,
                                                 float* __restrict__ ctx, int d) {
  int sb = blockIdx.x, tid = threadIdx.x;
  size_t cbase = (size_t)sb * 64 * H;
  for (int idx = tid; idx < 64 * H; idx += 512) ctx[cbase + idx] = 0.f;
  if (tid < 64) denom[sb * 64 + tid] = 0.f;
  __shared__ float mred;
  if (tid < 64) {
    float en = -INFINITY;
    if (depth[sb * 64 + tid] == d) en = energy[sb * 64 + tid];
    en = fmaxf(en, __shfl_xor(en, 1));  en = fmaxf(en, __shfl_xor(en, 2));
    en = fmaxf(en, __shfl_xor(en, 4));  en = fmaxf(en, __shfl_xor(en, 8));
    en = fmaxf(en, __shfl_xor(en, 16)); en = fmaxf(en, __shfl_xor(en, 32));
    if (tid == 0) mred = en;
  }
  __syncthreads();
  float m = mred;
  if (m == -INFINITY) return;
  for (int c = 0; c < 64; ++c) {
    if (depth[sb * 64 + c] != d) continue;
    float e = expf(energy[sb * 64 + c] - m);
    int p = parent[sb * 64 + c];
    ctx[cbase + (size_t)p * H + tid] += e * node[cbase + (size_t)c * H + tid];
    if (tid == 0) denom[sb * 64 + p] += e;
  }
}

// ---------------- parent update ----------------
__global__ __launch_bounds__(512) void k_update(const float* __restrict__ denom,
                                                const float* __restrict__ ctx,
                                                const float* __restrict__ wout,
                                                const float* __restrict__ Wc,
                                                float* __restrict__ node) {
  int sb = blockIdx.x, tid = threadIdx.x;
  __shared__ float cat[8][1024];
  __shared__ int plist[64];
  __shared__ int pcount;
  if (tid == 0) {
    int cnt = 0;
    for (int p = 0; p < 64; ++p) if (denom[sb * 64 + p] > 0.f) plist[cnt++] = p;
    pcount = cnt;
  }
  __syncthreads();
  int cnt = pcount;
  for (int p0 = 0; p0 < cnt; p0 += 8) {
    int nc = min(8, cnt - p0);
    __syncthreads();
    for (int r = 0; r < 16; ++r) {
      int idx = r * 512 + tid;
      int cc = idx >> 10, i = idx & 1023;
      if (cc < nc) {
        int p = plist[p0 + cc];
        size_t base = ((size_t)sb * 64 + p) * H;
        cat[cc][i] = (i < H) ? (ctx[base + i] / denom[sb * 64 + p]) : wout[base + i - H];
      }
    }
    __syncthreads();
    float acc[8] = {0, 0, 0, 0, 0, 0, 0, 0};
    for (int i = 0; i < 1024; ++i) {
      float w = Wc[(size_t)i * H + tid];
      #pragma unroll
      for (int cc = 0; cc < 8; ++cc) acc[cc] += cat[cc][i] * w;
    }
    for (int cc = 0; cc < nc; ++cc) {
      int p = plist[p0 + cc];
      node[((size_t)sb * 64 + p) * H + tid] = tanhf(acc[cc]);
    }
  }
}

// ---------------- span input ----------------
__global__ void k_xsp(const float* __restrict__ node, const float* __restrict__ pe,
                      float* __restrict__ xsp) {
  int i = blockIdx.x * 256 + threadIdx.x;     // 16384
  int j = i & 511, s = (i >> 9) & 3, b = i >> 11;
  xsp[i] = node[((size_t)(s * B + b) * 64 + 0) * H + j] + pe[s * H + j];
}

// ---------------- span attention scores ----------------
__global__ __launch_bounds__(512) void k_scspan(const float* __restrict__ xsp,
                                                const float* __restrict__ Wa,
                                                const float* __restrict__ va,
                                                const int* __restrict__ slen,
                                                float* __restrict__ sc) {
  int bi = blockIdx.x;                        // 128 blocks
  int b = bi >> 4, q = (bi >> 2) & 3, k = bi & 3;
  int tid = threadIdx.x;
  __shared__ float cat[1024];
  __shared__ float red[8];
  cat[tid] = xsp[(size_t)(b * S + q) * H + tid];
  cat[H + tid] = xsp[(size_t)(b * S + k) * H + tid];
  __syncthreads();
  float acc = 0.f;
  for (int i = 0; i < 1024; ++i) acc += cat[i] * Wa[(size_t)i * H + tid];
  float v = waveRedSum(va[tid] * tanhf(acc));
  int lane = tid & 63, wid = tid >> 6;
  if (lane == 0) red[wid] = v;
  __syncthreads();
  if (tid == 0) {
    float t = 0.f;
    for (int w = 0; w < 8; ++w) t += red[w];
    if (k >= slen[b]) t = -1e9f;
    sc[bi] = t;
  }
}

// ---------------- softmax over k + ctx ----------------
__global__ __launch_bounds__(512) void k_softctx(const float* __restrict__ sc,
                                                 const float* __restrict__ xsp,
                                                 float* __restrict__ sctx) {
  int bi = blockIdx.x;                        // 32 blocks
  int b = bi >> 2;
  int tid = threadIdx.x;
  float s0 = sc[bi * 4 + 0], s1 = sc[bi * 4 + 1], s2 = sc[bi * 4 + 2], s3 = sc[bi * 4 + 3];
  float m = fmaxf(fmaxf(s0, s1), fmaxf(s2, s3));
  float e0 = expf(s0 - m), e1 = expf(s1 - m), e2 = expf(s2 - m), e3 = expf(s3 - m);
  float inv = 1.f / (e0 + e1 + e2 + e3);
  float v = (e0 * xsp[(size_t)(b * S + 0) * H + tid] + e1 * xsp[(size_t)(b * S + 1) * H + tid] +
             e2 * xsp[(size_t)(b * S + 2) * H + tid] + e3 * xsp[(size_t)(b * S + 3) * H + tid]) * inv;
  sctx[(size_t)bi * H + tid] = v;
}

// ---------------- span output ----------------
__global__ __launch_bounds__(512) void k_spanout(const float* __restrict__ sctx,
                                                 const float* __restrict__ xsp,
                                                 const float* __restrict__ Wc,
                                                 const int* __restrict__ slen,
                                                 float* __restrict__ out) {
  int bi = blockIdx.x;                        // 32 blocks
  int b = bi >> 2, q = bi & 3;
  int tid = threadIdx.x;
  __shared__ float cat[1024];
  cat[tid] = sctx[(size_t)bi * H + tid];
  cat[H + tid] = xsp[(size_t)bi * H + tid];
  __syncthreads();
  float acc = 0.f;
  for (int i = 0; i < 1024; ++i) acc += cat[i] * Wc[(size_t)i * H + tid];
  float v = tanhf(acc);
  if (q >= slen[b]) v = 0.f;
  out[(size_t)bi * H + tid] = v;
}

// ---------------- span hidden ----------------
__global__ void k_spanhid(const float* __restrict__ spanout, const int* __restrict__ slen,
                          float* __restrict__ sh) {
  int i = blockIdx.x * 256 + threadIdx.x;     // 4096
  int b = i >> 9, j = i & 511;
  int q = slen[b] - 1;
  sh[i] = spanout[(size_t)(b * S + q) * H + j];
}

extern "C" void kernel_launch(void* const* d_in, const int* in_sizes, int n_in,
                              void* d_out, int out_size, void* d_ws, size_t ws_size,
                              hipStream_t stream) {
  (void)in_sizes; (void)n_in; (void)out_size; (void)ws_size;
  const int*   iv     = (const int*)d_in[0];
  const int*   slen   = (const int*)d_in[2];
  const int*   parent = (const int*)d_in[3];
  const int*   depth  = (const int*)d_in[4];
  const float* emb    = (const float*)d_in[5];
  const float* wih0   = (const float*)d_in[6];
  const float* whh0   = (const float*)d_in[7];
  const float* bih0   = (const float*)d_in[8];
  const float* bhh0   = (const float*)d_in[9];
  const float* wih1   = (const float*)d_in[10];
  const float* whh1   = (const float*)d_in[11];
  const float* bih1   = (const float*)d_in[12];
  const float* bhh1   = (const float*)d_in[13];
  const float* pe     = (const float*)d_in[14];
  const float* Wk     = (const float*)d_in[15];
  const float* Wa_s   = (const float*)d_in[16];
  const float* va_s   = (const float*)d_in[17];
  const float* Wc_s   = (const float*)d_in[18];
  const float* Wa_p   = (const float*)d_in[19];
  const float* va_p   = (const float*)d_in[20];
  const float* Wc_p   = (const float*)d_in[21];
  float* ws  = (float*)d_ws;
  float* out = (float*)d_out;

  // zero GRU hidden carry
  hipMemsetAsync(ws, 0, (2 * 2 * B * H) * sizeof(float), stream);

  // pack Whh (both layers) to bf16 once per launch
  k_pack<<<6144, 256, 0, stream>>>(whh0, (ushort_t*)(ws + WS_WB0));
  k_pack<<<6144, 256, 0, stream>>>(whh1, (ushort_t*)(ws + WS_WB1));

  k_embed<<<1024, 256, 0, stream>>>(iv, emb, ws + WS_EMB);
  k_wordop<<<128, 256, 0, stream>>>(ws + WS_EMB, Wk, out + O_WOP);
  k_sq<<<8, 256, 0, stream>>>(ws + WS_EMB, ws + WS_SQ);
  k_dist<<<2048, 256, 0, stream>>>(ws + WS_EMB, ws + WS_SQ,
                                   ws + WS_DIST, (double*)(ws + WS_BSUM));
  k_meansum<<<1, 256, 0, stream>>>((const double*)(ws + WS_BSUM), (double*)(ws + WS_MEAND));
  k_wordword<<<2048, 256, 0, stream>>>(ws + WS_DIST, (const double*)(ws + WS_MEAND),
                                       out + O_WW);
  k_depend<<<512, 256, 0, stream>>>(parent, out + O_DEP);

  for (int s = 0; s < S; ++s) {
    k_gemm_xg<<<dim3(8, 48), 256, 0, stream>>>(ws + WS_EMB + (size_t)s * B * L * E, wih0, bih0,
                                               ws + WS_XG0, E);
    k_gru<<<16, 1024, 0, stream>>>(ws + WS_XG0, (const ushort_t*)(ws + WS_WB0), bhh0,
                                   ws + WS_H, ws + WS_X1);
    k_gemm_xg<<<dim3(8, 48), 256, 0, stream>>>(ws + WS_X1, wih1, bih1, ws + WS_XG1, 2 * H);
    k_gru<<<16, 1024, 0, stream>>>(ws + WS_XG1, (const ushort_t*)(ws + WS_WB1), bhh1,
                                   ws + WS_H + 2 * B * H, ws + WS_O1);
    k_addwo<<<1024, 256, 0, stream>>>(ws + WS_O1, out + O_WORD + (size_t)s * B * L * H);
  }

  k_qpwnode<<<4096, 256, 0, stream>>>(out + O_WORD, parent, ws + WS_QPW, ws + WS_NODE);
  for (int d = 10; d >= 1; --d) {
    k_energy<<<32, 512, 0, stream>>>(depth, ws + WS_QPW, ws + WS_NODE, Wa_p, va_p, ws + WS_EN, d);
    k_scatter<<<32, 512, 0, stream>>>(depth, parent, ws + WS_EN, ws + WS_NODE,
                                      ws + WS_DEN, ws + WS_CTX, d);
    k_update<<<32, 512, 0, stream>>>(ws + WS_DEN, ws + WS_CTX, out + O_WORD, Wc_p, ws + WS_NODE);
  }

  k_xsp<<<64, 256, 0, stream>>>(ws + WS_NODE, pe, ws + WS_XSP);
  k_scspan<<<128, 512, 0, stream>>>(ws + WS_XSP, Wa_s, va_s, slen, ws + WS_SC);
  k_softctx<<<32, 512, 0, stream>>>(ws + WS_SC, ws + WS_XSP, ws + WS_SCTX);
  k_spanout<<<32, 512, 0, stream>>>(ws + WS_SCTX, ws + WS_XSP, Wc_s, slen, out + O_SPAN);
  k_spanhid<<<16, 256, 0, stream>>>(out + O_SPAN, slen, out + O_SH);
}